// Round 6
// baseline (954.532 us; speedup 1.0000x reference)
//
#include <hip/hip_runtime.h>
#include <math.h>

#define NPT 8192
#define CCH 128
#define KK  128

__device__ __forceinline__ unsigned f2key(float f) {
  unsigned u = __float_as_uint(f);
  return u ^ ((u & 0x80000000u) ? 0xFFFFFFFFu : 0x80000000u);
}
__device__ __forceinline__ float key2f(unsigned k) {
  unsigned u = (k & 0x80000000u) ? (k ^ 0x80000000u) : ~k;
  return __uint_as_float(u);
}

// ---------------- stats+moments zero ----------------
__global__ void k_zero(double* s) {
  int t = threadIdx.x;
  if (t < 76) s[t] = 0.0;  // 48 stats + 28 moments
}

// ---------------- corr GEMM (fp32, slab) ----------------
// grid (8, SR/16): block = 16 rows x 1024 cols, 4 cols/thread.
// A read via wave-uniform global loads -> s_load_dwordx16 (scalar cache),
// FMA takes SGPR operand directly. No LDS, no barriers.
__global__ __launch_bounds__(256, 2) void k_gemm(const float* __restrict__ A,
                                                 const float* __restrict__ B,
                                                 float* __restrict__ slab, int row0) {
  int tid = threadIdx.x;
  int rbase = row0 + blockIdx.y * 16;
  const float* Ap = A + rbase;   // Ap[c*NPT + r] is wave-uniform
  int m = blockIdx.x * 1024 + tid * 4;
  const float* Bp = B + m;
  float acc[16][4];
#pragma unroll
  for (int r = 0; r < 16; ++r) { acc[r][0] = acc[r][1] = acc[r][2] = acc[r][3] = 0.f; }
#pragma unroll 1
  for (int ct = 0; ct < CCH; ct += 8) {
    float4 bv[8];
#pragma unroll
    for (int j = 0; j < 8; ++j) bv[j] = *(const float4*)(Bp + (size_t)(ct + j) * NPT);
#pragma unroll
    for (int j = 0; j < 8; ++j) {
      const float* arow = Ap + (size_t)(ct + j) * NPT;
#pragma unroll
      for (int r = 0; r < 16; ++r) {
        float av = arow[r];  // uniform -> SGPR
        acc[r][0] += av * bv[j].x; acc[r][1] += av * bv[j].y;
        acc[r][2] += av * bv[j].z; acc[r][3] += av * bv[j].w;
      }
    }
  }
  const float sc = 0.08838834764831845f;  // 1/sqrt(128)
  int rl = blockIdx.y * 16;
#pragma unroll
  for (int r = 0; r < 16; ++r) {
    float4 o = make_float4(acc[r][0] * sc, acc[r][1] * sc, acc[r][2] * sc, acc[r][3] * sc);
    *(float4*)(slab + (size_t)(rl + r) * NPT + m) = o;
  }
}

// ---------------- exact per-row top-128: 2-bit-per-pass binary search ----------------
__global__ __launch_bounds__(256) void k_select(const float* __restrict__ slab, int row0,
                                                float* __restrict__ tcorr, int* __restrict__ tidx) {
  __shared__ int wcnt[2][4][3];
  __shared__ int sh_cnt;
  int tid = threadIdx.x, lane = tid & 63, wv = tid >> 6;
  const float* rowp = slab + (size_t)blockIdx.x * NPT;
  unsigned key[32];
#pragma unroll
  for (int j = 0; j < 32; ++j) key[j] = f2key(rowp[tid + j * 256]);
  if (tid == 0) sh_cnt = 0;
  unsigned P = 0;
  int par = 0;
#pragma unroll 1
  for (int b = 30; b >= 0; b -= 2) {
    unsigned T1 = P | (1u << b), T2 = P | (2u << b), T3 = P | (3u << b);
    int c1 = 0, c2 = 0, c3 = 0;
#pragma unroll
    for (int j = 0; j < 32; ++j) {
      unsigned k = key[j];
      c1 += (k >= T1) ? 1 : 0; c2 += (k >= T2) ? 1 : 0; c3 += (k >= T3) ? 1 : 0;
    }
    for (int off = 32; off; off >>= 1) {
      c1 += __shfl_down(c1, off); c2 += __shfl_down(c2, off); c3 += __shfl_down(c3, off);
    }
    if (lane == 0) { wcnt[par][wv][0] = c1; wcnt[par][wv][1] = c2; wcnt[par][wv][2] = c3; }
    __syncthreads();
    int t1 = wcnt[par][0][0] + wcnt[par][1][0] + wcnt[par][2][0] + wcnt[par][3][0];
    int t2 = wcnt[par][0][1] + wcnt[par][1][1] + wcnt[par][2][1] + wcnt[par][3][1];
    int t3 = wcnt[par][0][2] + wcnt[par][1][2] + wcnt[par][2][2] + wcnt[par][3][2];
    if (t3 >= KK) P = T3;
    else if (t2 >= KK) P = T2;
    else if (t1 >= KK) P = T1;
    par ^= 1;
  }
  int row = row0 + blockIdx.x;
#pragma unroll
  for (int j = 0; j < 32; ++j) {
    if (key[j] > P) {
      int pos = atomicAdd(&sh_cnt, 1);
      tcorr[(size_t)row * KK + pos] = key2f(key[j]);
      tidx[(size_t)row * KK + pos] = tid + j * 256;
    }
  }
  __syncthreads();
#pragma unroll
  for (int j = 0; j < 32; ++j) {
    if (key[j] == P) {
      int pos = atomicAdd(&sh_cnt, 1);
      if (pos < KK) {
        tcorr[(size_t)row * KK + pos] = key2f(P);
        tidx[(size_t)row * KK + pos] = tid + j * 256;
      }
    }
  }
}

// ---------------- per-point voxel/coarse/knn geometry ----------------
__global__ __launch_bounds__(128) void k_point(const float* __restrict__ tcorr,
                                               const int* __restrict__ tidx,
                                               const float* __restrict__ xyz2,
                                               const float* __restrict__ coords,
                                               float* __restrict__ feats,
                                               float* __restrict__ vox_in,
                                               float* __restrict__ knn_in) {
  __shared__ float px[128], py[128], pz[128];
  __shared__ float4 dd4s[32];
  __shared__ float cadd[81], ccnt[81];
  __shared__ unsigned long long cmax[27];
  __shared__ unsigned long long gmax;
  __shared__ float4 mvp[27];  // x,y,z, oob flag
  __shared__ float vadd[28];
  __shared__ int vcnt[28];
  int n = blockIdx.x, t = threadIdx.x;
  float v = tcorr[(size_t)n * KK + t];
  int idx = tidx[(size_t)n * KK + t];
  float p0 = xyz2[idx * 3 + 0], p1 = xyz2[idx * 3 + 1], p2 = xyz2[idx * 3 + 2];
  float c0 = coords[n * 3 + 0], c1 = coords[n * 3 + 1], c2 = coords[n * 3 + 2];
  px[t] = p0; py[t] = p1; pz[t] = p2;
  float dx = p0 - c0, dy = p1 - c1, dz = p2 - c2;
  float d = dx * dx + dy * dy + dz * dz;
  ((float*)dd4s)[t] = d;
  if (t < 81) { cadd[t] = 0.f; ccnt[t] = 0.f; }
  if (t < 27) cmax[t] = 0ULL;
  if (t < 28) { vadd[t] = 0.f; vcnt[t] = 0; }
  if (t == 0) gmax = 0ULL;
  __syncthreads();
#pragma unroll
  for (int lvl = 0; lvl < 3; ++lvl) {
    float rinv = (lvl == 0) ? 4.f : (lvl == 1) ? 2.f : 1.f;
    float d0 = rintf(dx * rinv), d1 = rintf(dy * rinv), d2 = rintf(dz * rinv);
    if (fabsf(d0) <= 1.f && fabsf(d1) <= 1.f && fabsf(d2) <= 1.f) {
      int cube = (int)(d0 + 1.f) * 9 + (int)(d1 + 1.f) * 3 + (int)(d2 + 1.f);
      atomicAdd(&cadd[lvl * 27 + cube], v);
      atomicAdd(&ccnt[lvl * 27 + cube], 1.f);
    }
  }
  unsigned long long pk = (((unsigned long long)f2key(v)) << 32) | (unsigned)t;
  atomicMax(&gmax, pk);
  {
    float d0 = rintf(dx * 0.25f), d1 = rintf(dy * 0.25f), d2 = rintf(dz * 0.25f);
    if (fabsf(d0) <= 1.5f && fabsf(d1) <= 1.5f && fabsf(d2) <= 1.5f) {
      int bin = (int)(d0 + 1.f) * 9 + (int)(d1 + 1.f) * 3 + (int)(d2 + 1.f);
      atomicMax(&cmax[bin], pk);
    }
  }
  __syncthreads();
  if (t < 27) {
    unsigned long long pkb = cmax[t];
    unsigned hi = (unsigned)(pkb >> 32);
    int ob = (hi <= 0x80000000u) ? 1 : 0;
    int ki = ob ? (int)(gmax & 0xFFFFFFFFULL) : (int)(pkb & 0xFFFFFFFFULL);
    float ccx = px[ki], ccy = py[ki], ccz = pz[ki];
    float bx = (float)(t / 9 - 1), by = (float)((t / 3) % 3 - 1), bz = (float)(t % 3 - 1);
    float vk0 = c0 + bx * 4.f, vk1 = c1 + by * 4.f, vk2 = c2 + bz * 4.f;
    float m0 = fminf(fmaxf(ccx - vk0, -1.f), 1.f) + vk0;
    float m1 = fminf(fmaxf(ccy - vk1, -1.f), 1.f) + vk1;
    float m2 = fminf(fmaxf(ccz - vk2, -1.f), 1.f) + vk2;
    mvp[t] = make_float4(m0, m1, m2, ob ? 1.f : 0.f);
    float* vp = vox_in + ((size_t)n * 27 + t) * 4;
    vp[1] = m0; vp[2] = m1; vp[3] = m2;
  }
  __syncthreads();
  int is = 27;
#pragma unroll 1
  for (int b = 0; b < 27; ++b) {
    float4 mv = mvp[b];
    if (mv.w == 0.f && fabsf(p0 - mv.x) <= 1.f && fabsf(p1 - mv.y) <= 1.f &&
        fabsf(p2 - mv.z) <= 1.f)
      is = b;
  }
  atomicAdd(&vadd[is], v);
  atomicAdd(&vcnt[is], 1);
  __syncthreads();
  if (t < 27) {
    float cnt = fmaxf((float)vcnt[t], 1.f);
    vox_in[((size_t)n * 27 + t) * 4 + 0] = vadd[t] / cnt;
  }
  if (t < 81) {
    float cnt = fminf(fmaxf(ccnt[t], 1.f), 8192.f);
    feats[(size_t)t * NPT + n] = cadd[t] / cnt;
  }
  int rank = 0;
#pragma unroll 4
  for (int j4 = 0; j4 < 32; ++j4) {
    float4 dj = dd4s[j4];
    int jb = j4 * 4;
    rank += (dj.x < d || (dj.x == d && jb + 0 < t)) ? 1 : 0;
    rank += (dj.y < d || (dj.y == d && jb + 1 < t)) ? 1 : 0;
    rank += (dj.z < d || (dj.z == d && jb + 2 < t)) ? 1 : 0;
    rank += (dj.w < d || (dj.w == d && jb + 3 < t)) ? 1 : 0;
  }
  if (rank < 32) {
    float* kp = knn_in + ((size_t)n * 32 + rank) * 4;
    *(float4*)kp = make_float4(v, dx, dy, dz);
  }
}

// ---------------- input moments for GN stats (conv is linear) ----------------
__global__ __launch_bounds__(256) void k_moments(const float* __restrict__ vox_in,
                                                 const float* __restrict__ knn_in,
                                                 double* __restrict__ mom) {
  int b = blockIdx.x, t = threadIdx.x;
  int isknn = (b >= 256) ? 1 : 0;
  const float* src = isknn ? knn_in : vox_in;
  int nsite = isknn ? NPT * 32 : NPT * 27;
  int base = isknn ? 14 : 0;
  int bb = isknn ? b - 256 : b;
  float S0 = 0, S1 = 0, S2 = 0, S3 = 0;
  float M00 = 0, M01 = 0, M02 = 0, M03 = 0, M11 = 0, M12 = 0, M13 = 0, M22 = 0, M23 = 0, M33 = 0;
  for (int s = bb * 256 + t; s < nsite; s += 256 * 256) {
    float4 x = *(const float4*)(src + (size_t)s * 4);
    S0 += x.x; S1 += x.y; S2 += x.z; S3 += x.w;
    M00 += x.x * x.x; M01 += x.x * x.y; M02 += x.x * x.z; M03 += x.x * x.w;
    M11 += x.y * x.y; M12 += x.y * x.z; M13 += x.y * x.w;
    M22 += x.z * x.z; M23 += x.z * x.w; M33 += x.w * x.w;
  }
  float vals[14] = {S0, S1, S2, S3, M00, M01, M02, M03, M11, M12, M13, M22, M23, M33};
  for (int off = 32; off; off >>= 1)
#pragma unroll
    for (int i = 0; i < 14; ++i) vals[i] += __shfl_down(vals[i], off);
  __shared__ float part[14];
  if (t < 14) part[t] = 0.f;
  __syncthreads();
  if ((t & 63) == 0)
#pragma unroll
    for (int i = 0; i < 14; ++i) atomicAdd(&part[i], vals[i]);
  __syncthreads();
  if (t < 14) atomicAdd(&mom[base + t], (double)part[t]);
}

// ---------------- finalize GN stats from moments ----------------
__global__ void k_stats_fin(const float* __restrict__ vw1, const float* __restrict__ vb1,
                            const float* __restrict__ kw1, const float* __restrict__ kb1,
                            const double* __restrict__ mom, double* __restrict__ stats) {
  int t = threadIdx.x;
  if (t >= 16) return;
  int isknn = (t >= 8) ? 1 : 0;
  const double* m = mom + (isknn ? 14 : 0);
  const float* W = isknn ? kw1 : vw1;
  const float* Bi = isknn ? kb1 : vb1;
  double N = isknn ? (double)NPT * 32.0 : (double)NPT * 27.0;
  int per = isknn ? 8 : 4;
  int g = isknn ? t - 8 : t;
  double S0 = m[0], S1 = m[1], S2 = m[2], S3 = m[3];
  double M00 = m[4], M01 = m[5], M02 = m[6], M03 = m[7];
  double M11 = m[8], M12 = m[9], M13 = m[10], M22 = m[11], M23 = m[12], M33 = m[13];
  double sum = 0.0, ssq = 0.0;
  for (int k = 0; k < per; ++k) {
    int oc = g * per + k;
    double w0 = W[oc * 4 + 0], w1 = W[oc * 4 + 1], w2 = W[oc * 4 + 2], w3 = W[oc * 4 + 3];
    double b = Bi[oc];
    double ws = w0 * S0 + w1 * S1 + w2 * S2 + w3 * S3;
    double q = w0 * w0 * M00 + w1 * w1 * M11 + w2 * w2 * M22 + w3 * w3 * M33 +
               2.0 * (w0 * w1 * M01 + w0 * w2 * M02 + w0 * w3 * M03 +
                      w1 * w2 * M12 + w1 * w3 * M13 + w2 * w3 * M23);
    sum += ws + N * b;
    ssq += q + 2.0 * b * ws + N * b * b;
  }
  double* out = stats + (isknn ? 16 : 0);
  out[2 * g + 0] = sum;
  out[2 * g + 1] = ssq;
}

// ---------------- vox branch apply ----------------
__global__ __launch_bounds__(256) void k_vox_apply(const float* __restrict__ vox_in,
                                                   const float* __restrict__ w1,
                                                   const float* __restrict__ b1,
                                                   const float* __restrict__ gamma,
                                                   const float* __restrict__ beta,
                                                   const float* __restrict__ pr,
                                                   const float* __restrict__ w2,
                                                   const float* __restrict__ b2,
                                                   const double* __restrict__ stats,
                                                   float* __restrict__ feats) {
  int s = blockIdx.x * 256 + threadIdx.x;
  if (s >= NPT * 27) return;
  float mean[8], rstd[8];
  const double cntd = 4.0 * 8192.0 * 27.0;
#pragma unroll
  for (int g = 0; g < 8; ++g) {
    double m = stats[2 * g] / cntd;
    double var = stats[2 * g + 1] / cntd - m * m;
    mean[g] = (float)m;
    rstd[g] = (float)(1.0 / sqrt(var + 1e-5));
  }
  float a = pr[0];
  float4 in = *(const float4*)(vox_in + (size_t)s * 4);
  float out = b2[0];
#pragma unroll
  for (int oc = 0; oc < 32; ++oc) {
    float4 w = *(const float4*)(w1 + oc * 4);
    float h = w.x * in.x + w.y * in.y + w.z * in.z + w.w * in.w + b1[oc];
    int g = oc >> 2;
    float xn = (h - mean[g]) * rstd[g] * gamma[oc] + beta[oc];
    float y = (xn >= 0.f) ? xn : a * xn;
    out += w2[oc] * y;
  }
  int n = s / 27, bb = s - n * 27;
  feats[(size_t)(81 + bb) * NPT + n] = out;
}

// ---------------- knn apply: GN+PReLU, max over 32 -> kf (64 x N) ----------------
__global__ __launch_bounds__(256) void k_knn_max(const float* __restrict__ knn_in,
                                                 const float* __restrict__ w1,
                                                 const float* __restrict__ b1,
                                                 const float* __restrict__ gamma,
                                                 const float* __restrict__ beta,
                                                 const float* __restrict__ pr,
                                                 const double* __restrict__ stats,
                                                 float* __restrict__ kf) {
  int tid0 = blockIdx.x * 256 + threadIdx.x;
  int n = tid0 & (NPT - 1);
  int oc = tid0 >> 13;
  const double cntd = 8.0 * 8192.0 * 32.0;
  int g = oc >> 3;
  double md = stats[2 * g] / cntd;
  double var = stats[2 * g + 1] / cntd - md * md;
  float mean = (float)md, rstd = (float)(1.0 / sqrt(var + 1e-5));
  float4 w = *(const float4*)(w1 + oc * 4);
  float bb = b1[oc], ga = gamma[oc], be = beta[oc], a = pr[0];
  float mx = -INFINITY;
  for (int j = 0; j < 32; ++j) {
    float4 in = *(const float4*)(knn_in + ((size_t)n * 32 + j) * 4);
    float h = w.x * in.x + w.y * in.y + w.z * in.z + w.w * in.w + bb;
    float xn = (h - mean) * rstd * ga + be;
    float y = (xn >= 0.f) ? xn : a * xn;
    mx = fmaxf(mx, y);
  }
  kf[(size_t)oc * NPT + n] = mx;
}

// ---------------- out branch conv1 (108->128) + GN stats ----------------
__global__ __launch_bounds__(256) void k_out1(const float* __restrict__ feats,
                                              const float* __restrict__ w1,
                                              const float* __restrict__ b1,
                                              float* __restrict__ h1,
                                              double* __restrict__ stats) {
  __shared__ float wlds[108 * 16];
  __shared__ float ls, lq;
  int t = threadIdx.x;
  int ocb = blockIdx.y * 16;
  for (int i = t; i < 108 * 16; i += 256) {
    int j = i / 108, ic = i - j * 108;
    wlds[ic * 16 + j] = w1[ocb * 108 + i];
  }
  if (t == 0) { ls = 0.f; lq = 0.f; }
  __syncthreads();
  int n = blockIdx.x * 256 + t;
  float acc[16];
#pragma unroll
  for (int j = 0; j < 16; ++j) acc[j] = b1[ocb + j];
#pragma unroll 4
  for (int ic = 0; ic < 108; ++ic) {
    float v = feats[(size_t)ic * NPT + n];
    const float4* w4 = (const float4*)(wlds + ic * 16);
#pragma unroll
    for (int q = 0; q < 4; ++q) {
      float4 w = w4[q];
      acc[q * 4 + 0] += w.x * v; acc[q * 4 + 1] += w.y * v;
      acc[q * 4 + 2] += w.z * v; acc[q * 4 + 3] += w.w * v;
    }
  }
  float s = 0.f, q = 0.f;
#pragma unroll
  for (int j = 0; j < 16; ++j) {
    h1[(size_t)(ocb + j) * NPT + n] = acc[j];
    s += acc[j]; q += acc[j] * acc[j];
  }
  for (int off = 32; off; off >>= 1) { s += __shfl_down(s, off); q += __shfl_down(q, off); }
  if ((t & 63) == 0) { atomicAdd(&ls, s); atomicAdd(&lq, q); }
  __syncthreads();
  if (t == 0) {
    atomicAdd(&stats[2 * blockIdx.y + 0], (double)ls);
    atomicAdd(&stats[2 * blockIdx.y + 1], (double)lq);
  }
}

// ---------------- final: GN+PReLU on h1, conv(128->64) + conv(64->64)(kf) ----------------
__global__ __launch_bounds__(256) void k_final(const float* __restrict__ h1,
                                               const float* __restrict__ kf,
                                               const float* __restrict__ gamma,
                                               const float* __restrict__ beta,
                                               const float* __restrict__ pr,
                                               const float* __restrict__ w2,
                                               const float* __restrict__ b2,
                                               const float* __restrict__ kow,
                                               const float* __restrict__ kob,
                                               const double* __restrict__ stats,
                                               float* __restrict__ out) {
  __shared__ float wl[192 * 8];
  __shared__ float scl[128], sft[128];
  int t = threadIdx.x;
  int ocb = blockIdx.y * 8;
  for (int i = t; i < 128 * 8; i += 256) {
    int j = i >> 7, ic = i & 127;
    wl[ic * 8 + j] = w2[(ocb + j) * 128 + ic];
  }
  for (int i = t; i < 64 * 8; i += 256) {
    int j = i >> 6, ic = i & 63;
    wl[(128 + ic) * 8 + j] = kow[(ocb + j) * 64 + ic];
  }
  if (t < 128) {
    const double cntd = 16.0 * 8192.0;
    int g = t >> 4;
    double m = stats[2 * g] / cntd;
    double var = stats[2 * g + 1] / cntd - m * m;
    float rs = (float)(1.0 / sqrt(var + 1e-5));
    float ga = gamma[t];
    scl[t] = rs * ga;
    sft[t] = beta[t] - (float)m * rs * ga;
  }
  __syncthreads();
  int n = blockIdx.x * 256 + t;
  float a = pr[0];
  float acc[8];
#pragma unroll
  for (int j = 0; j < 8; ++j) acc[j] = b2[ocb + j] + kob[ocb + j];
#pragma unroll 2
  for (int ic = 0; ic < 128; ++ic) {
    float x = h1[(size_t)ic * NPT + n];
    float xn = x * scl[ic] + sft[ic];
    float y = (xn >= 0.f) ? xn : a * xn;
    const float4* w4 = (const float4*)(wl + ic * 8);
    float4 wa = w4[0], wb = w4[1];
    acc[0] += wa.x * y; acc[1] += wa.y * y; acc[2] += wa.z * y; acc[3] += wa.w * y;
    acc[4] += wb.x * y; acc[5] += wb.y * y; acc[6] += wb.z * y; acc[7] += wb.w * y;
  }
#pragma unroll 2
  for (int ic = 0; ic < 64; ++ic) {
    float y = kf[(size_t)ic * NPT + n];
    const float4* w4 = (const float4*)(wl + (128 + ic) * 8);
    float4 wa = w4[0], wb = w4[1];
    acc[0] += wa.x * y; acc[1] += wa.y * y; acc[2] += wa.z * y; acc[3] += wa.w * y;
    acc[4] += wb.x * y; acc[5] += wb.y * y; acc[6] += wb.z * y; acc[7] += wb.w * y;
  }
#pragma unroll
  for (int j = 0; j < 8; ++j)
    out[(size_t)(ocb + j) * NPT + n] = acc[j];
}

extern "C" void kernel_launch(void* const* d_in, const int* in_sizes, int n_in,
                              void* d_out, int out_size, void* d_ws, size_t ws_size,
                              hipStream_t stream) {
  (void)in_sizes; (void)n_in; (void)out_size;
  const float* fmap1  = (const float*)d_in[0];
  const float* fmap2  = (const float*)d_in[1];
  const float* xyz2   = (const float*)d_in[2];
  const float* coords = (const float*)d_in[3];
  const float* out_w1 = (const float*)d_in[4];
  const float* out_b1 = (const float*)d_in[5];
  const float* out_g  = (const float*)d_in[6];
  const float* out_bt = (const float*)d_in[7];
  const float* out_pr = (const float*)d_in[8];
  const float* out_w2 = (const float*)d_in[9];
  const float* out_b2 = (const float*)d_in[10];
  const float* vox_w1 = (const float*)d_in[11];
  const float* vox_b1 = (const float*)d_in[12];
  const float* vox_g  = (const float*)d_in[13];
  const float* vox_bt = (const float*)d_in[14];
  const float* vox_pr = (const float*)d_in[15];
  const float* vox_w2 = (const float*)d_in[16];
  const float* vox_b2 = (const float*)d_in[17];
  const float* knn_w1 = (const float*)d_in[18];
  const float* knn_b1 = (const float*)d_in[19];
  const float* knn_g  = (const float*)d_in[20];
  const float* knn_bt = (const float*)d_in[21];
  const float* knn_pr = (const float*)d_in[22];
  const float* knn_ow = (const float*)d_in[23];
  const float* knn_ob = (const float*)d_in[24];

  float* ws = (float*)d_ws;
  const size_t nonslab = 6488064ull;
  int SR;
  if (ws_size >= (8388608ull + nonslab) * 4ull + 1024ull) SR = 1024;
  else if (ws_size >= (4194304ull + nonslab) * 4ull + 1024ull) SR = 512;
  else SR = 256;

  float* slab   = ws;
  float* tcorr  = slab + (size_t)SR * NPT;
  int*   tidx   = (int*)(tcorr + (size_t)NPT * KK);
  float* feats  = tcorr + (size_t)NPT * KK * 2;
  float* vox_in = feats + 108 * NPT;
  float* knn_in = vox_in + (size_t)NPT * 27 * 4;
  float* h1     = knn_in + (size_t)NPT * 32 * 4;
  float* kf     = h1 + 128 * NPT;
  double* stats = (double*)(kf + 64 * NPT);
  double* mom   = stats + 48;

  hipLaunchKernelGGL(k_zero, dim3(1), dim3(128), 0, stream, stats);
  int iters = NPT / SR;
  for (int s = 0; s < iters; ++s) {
    hipLaunchKernelGGL(k_gemm, dim3(8, SR / 16), dim3(256), 0, stream, fmap1, fmap2, slab, s * SR);
    hipLaunchKernelGGL(k_select, dim3(SR), dim3(256), 0, stream, slab, s * SR, tcorr, tidx);
  }
  hipLaunchKernelGGL(k_point, dim3(NPT), dim3(128), 0, stream, tcorr, tidx, xyz2, coords,
                     feats, vox_in, knn_in);
  hipLaunchKernelGGL(k_moments, dim3(512), dim3(256), 0, stream, vox_in, knn_in, mom);
  hipLaunchKernelGGL(k_stats_fin, dim3(1), dim3(64), 0, stream, vox_w1, vox_b1, knn_w1, knn_b1,
                     mom, stats);
  hipLaunchKernelGGL(k_vox_apply, dim3((NPT * 27 + 255) / 256), dim3(256), 0, stream, vox_in,
                     vox_w1, vox_b1, vox_g, vox_bt, vox_pr, vox_w2, vox_b2, stats, feats);
  hipLaunchKernelGGL(k_knn_max, dim3(64 * NPT / 256), dim3(256), 0, stream, knn_in, knn_w1,
                     knn_b1, knn_g, knn_bt, knn_pr, stats + 16, kf);
  hipLaunchKernelGGL(k_out1, dim3(32, 8), dim3(256), 0, stream, feats, out_w1, out_b1, h1,
                     stats + 32);
  hipLaunchKernelGGL(k_final, dim3(32, 8), dim3(256), 0, stream, h1, kf, out_g, out_bt,
                     out_pr, out_w2, out_b2, knn_ow, knn_ob, stats + 32, (float*)d_out);
}

// Round 7
// 796.037 us; speedup vs baseline: 1.1991x; 1.1991x over previous
//
#include <hip/hip_runtime.h>
#include <math.h>

#define NPT 8192
#define CCH 128
#define KK  128

typedef __attribute__((ext_vector_type(8))) short short8;
typedef __attribute__((ext_vector_type(4))) float f32x4;

__device__ __forceinline__ unsigned f2key(float f) {
  unsigned u = __float_as_uint(f);
  return u ^ ((u & 0x80000000u) ? 0xFFFFFFFFu : 0x80000000u);
}
__device__ __forceinline__ float key2f(unsigned k) {
  unsigned u = (k & 0x80000000u) ? (k ^ 0x80000000u) : ~k;
  return __uint_as_float(u);
}

// ---------------- stats+moments zero ----------------
__global__ void k_zero(double* s) {
  int t = threadIdx.x;
  if (t < 76) s[t] = 0.0;  // 48 stats + 28 moments
}

// ---------------- fp32 -> bf16x3 exact split, MFMA-blocked layout ----------------
// src [c][n] (c-major, stride NPT). Output [g][oct][m][j]: g=n>>4, m=n&15,
// oct=c>>3, j=c&7 — so a 16B load at ((g*16+oct)*16+m)*8 is one A/B fragment slice.
__global__ __launch_bounds__(256) void k_split(const float* __restrict__ src,
                                               short* __restrict__ d0,
                                               short* __restrict__ d1,
                                               short* __restrict__ d2) {
  __shared__ float tile[2048];  // [c][m]
  int g = blockIdx.x, t = threadIdx.x;
#pragma unroll
  for (int p = 0; p < 8; ++p) {
    int i = t + p * 256;
    int c = i >> 4, m = i & 15;
    tile[i] = src[(size_t)c * NPT + g * 16 + m];
  }
  __syncthreads();
  int o = t >> 4, m = t & 15;
  short8 w0, w1, w2;
#pragma unroll
  for (int j = 0; j < 8; ++j) {
    float a = tile[(o * 8 + j) * 16 + m];
    unsigned ua = __float_as_uint(a);
    unsigned uh = ua & 0xFFFF0000u;
    float r = a - __uint_as_float(uh);          // exact
    unsigned um = __float_as_uint(r) & 0xFFFF0000u;
    float r2 = r - __uint_as_float(um);         // exact
    unsigned ul = __float_as_uint(r2) & 0xFFFF0000u;
    w0[j] = (short)(uh >> 16);
    w1[j] = (short)(um >> 16);
    w2[j] = (short)(ul >> 16);
  }
  size_t base = (((size_t)g * 16 + o) * 16 + m) * 8;
  *(short8*)(d0 + base) = w0;
  *(short8*)(d1 + base) = w1;
  *(short8*)(d2 + base) = w2;
}

// ---------------- corr GEMM via bf16x3 MFMA (fp32-accurate) ----------------
// grid (64, SR/64), 4 waves/block. Wave = 16 rows x 128 cols (8 16x16 tiles).
// 6 MFMA terms per k-step reproduce the fp32 product to ~2^-24.
__global__ __launch_bounds__(256) void k_gemm_mfma(
    const short* __restrict__ a0, const short* __restrict__ a1, const short* __restrict__ a2,
    const short* __restrict__ b0, const short* __restrict__ b1, const short* __restrict__ b2,
    float* __restrict__ slab, int row0) {
  int tid = threadIdx.x;
  int wv = tid >> 6, lane = tid & 63;
  int m15 = lane & 15, quad = lane >> 4;
  int rowg = (row0 >> 4) + blockIdx.y * 4 + wv;  // global 16-row group
  int colg0 = blockIdx.x * 8;                    // first 16-col group
  f32x4 acc[8];
#pragma unroll
  for (int t = 0; t < 8; ++t) acc[t] = (f32x4){0.f, 0.f, 0.f, 0.f};
#pragma unroll
  for (int s = 0; s < 4; ++s) {
    int oct = s * 4 + quad;
    size_t abase = (((size_t)rowg * 16 + oct) * 16 + m15) * 8;
    short8 A0 = *(const short8*)(a0 + abase);
    short8 A1 = *(const short8*)(a1 + abase);
    short8 A2 = *(const short8*)(a2 + abase);
#pragma unroll
    for (int t = 0; t < 8; ++t) {
      size_t bbase = (((size_t)(colg0 + t) * 16 + oct) * 16 + m15) * 8;
      short8 B0 = *(const short8*)(b0 + bbase);
      short8 B1 = *(const short8*)(b1 + bbase);
      short8 B2 = *(const short8*)(b2 + bbase);
      acc[t] = __builtin_amdgcn_mfma_f32_16x16x32_bf16(A2, B0, acc[t], 0, 0, 0);
      acc[t] = __builtin_amdgcn_mfma_f32_16x16x32_bf16(A0, B2, acc[t], 0, 0, 0);
      acc[t] = __builtin_amdgcn_mfma_f32_16x16x32_bf16(A1, B1, acc[t], 0, 0, 0);
      acc[t] = __builtin_amdgcn_mfma_f32_16x16x32_bf16(A1, B0, acc[t], 0, 0, 0);
      acc[t] = __builtin_amdgcn_mfma_f32_16x16x32_bf16(A0, B1, acc[t], 0, 0, 0);
      acc[t] = __builtin_amdgcn_mfma_f32_16x16x32_bf16(A0, B0, acc[t], 0, 0, 0);
    }
  }
  const float sc = 0.08838834764831845f;  // 1/sqrt(128)
  int rl = (blockIdx.y * 4 + wv) * 16 + quad * 4;
#pragma unroll
  for (int t = 0; t < 8; ++t) {
    int col = (colg0 + t) * 16 + m15;
#pragma unroll
    for (int r = 0; r < 4; ++r)
      slab[(size_t)(rl + r) * NPT + col] = acc[t][r] * sc;
  }
}

// ---------------- exact per-row top-128: 2-bit-per-pass binary search ----------------
__global__ __launch_bounds__(256) void k_select(const float* __restrict__ slab, int row0,
                                                float* __restrict__ tcorr, int* __restrict__ tidx) {
  __shared__ int wcnt[2][4][3];
  __shared__ int sh_cnt;
  int tid = threadIdx.x, lane = tid & 63, wv = tid >> 6;
  const float* rowp = slab + (size_t)blockIdx.x * NPT;
  unsigned key[32];
#pragma unroll
  for (int j = 0; j < 32; ++j) key[j] = f2key(rowp[tid + j * 256]);
  if (tid == 0) sh_cnt = 0;
  unsigned P = 0;
  int par = 0;
#pragma unroll 1
  for (int b = 30; b >= 0; b -= 2) {
    unsigned T1 = P | (1u << b), T2 = P | (2u << b), T3 = P | (3u << b);
    int c1 = 0, c2 = 0, c3 = 0;
#pragma unroll
    for (int j = 0; j < 32; ++j) {
      unsigned k = key[j];
      c1 += (k >= T1) ? 1 : 0; c2 += (k >= T2) ? 1 : 0; c3 += (k >= T3) ? 1 : 0;
    }
    for (int off = 32; off; off >>= 1) {
      c1 += __shfl_down(c1, off); c2 += __shfl_down(c2, off); c3 += __shfl_down(c3, off);
    }
    if (lane == 0) { wcnt[par][wv][0] = c1; wcnt[par][wv][1] = c2; wcnt[par][wv][2] = c3; }
    __syncthreads();
    int t1 = wcnt[par][0][0] + wcnt[par][1][0] + wcnt[par][2][0] + wcnt[par][3][0];
    int t2 = wcnt[par][0][1] + wcnt[par][1][1] + wcnt[par][2][1] + wcnt[par][3][1];
    int t3 = wcnt[par][0][2] + wcnt[par][1][2] + wcnt[par][2][2] + wcnt[par][3][2];
    if (t3 >= KK) P = T3;
    else if (t2 >= KK) P = T2;
    else if (t1 >= KK) P = T1;
    par ^= 1;
  }
  int row = row0 + blockIdx.x;
#pragma unroll
  for (int j = 0; j < 32; ++j) {
    if (key[j] > P) {
      int pos = atomicAdd(&sh_cnt, 1);
      tcorr[(size_t)row * KK + pos] = key2f(key[j]);
      tidx[(size_t)row * KK + pos] = tid + j * 256;
    }
  }
  __syncthreads();
#pragma unroll
  for (int j = 0; j < 32; ++j) {
    if (key[j] == P) {
      int pos = atomicAdd(&sh_cnt, 1);
      if (pos < KK) {
        tcorr[(size_t)row * KK + pos] = key2f(P);
        tidx[(size_t)row * KK + pos] = tid + j * 256;
      }
    }
  }
}

// ---------------- per-point voxel/coarse/knn geometry ----------------
__global__ __launch_bounds__(128) void k_point(const float* __restrict__ tcorr,
                                               const int* __restrict__ tidx,
                                               const float* __restrict__ xyz2,
                                               const float* __restrict__ coords,
                                               float* __restrict__ feats,
                                               float* __restrict__ vox_in,
                                               float* __restrict__ knn_in) {
  __shared__ float px[128], py[128], pz[128];
  __shared__ float4 dd4s[32];
  __shared__ float cadd[81], ccnt[81];
  __shared__ unsigned long long cmax[27];
  __shared__ unsigned long long gmax;
  __shared__ float4 mvp[27];  // x,y,z, oob flag
  __shared__ float vadd[28];
  __shared__ int vcnt[28];
  int n = blockIdx.x, t = threadIdx.x;
  float v = tcorr[(size_t)n * KK + t];
  int idx = tidx[(size_t)n * KK + t];
  float p0 = xyz2[idx * 3 + 0], p1 = xyz2[idx * 3 + 1], p2 = xyz2[idx * 3 + 2];
  float c0 = coords[n * 3 + 0], c1 = coords[n * 3 + 1], c2 = coords[n * 3 + 2];
  px[t] = p0; py[t] = p1; pz[t] = p2;
  float dx = p0 - c0, dy = p1 - c1, dz = p2 - c2;
  float d = dx * dx + dy * dy + dz * dz;
  ((float*)dd4s)[t] = d;
  if (t < 81) { cadd[t] = 0.f; ccnt[t] = 0.f; }
  if (t < 27) cmax[t] = 0ULL;
  if (t < 28) { vadd[t] = 0.f; vcnt[t] = 0; }
  if (t == 0) gmax = 0ULL;
  __syncthreads();
#pragma unroll
  for (int lvl = 0; lvl < 3; ++lvl) {
    float rinv = (lvl == 0) ? 4.f : (lvl == 1) ? 2.f : 1.f;
    float d0 = rintf(dx * rinv), d1 = rintf(dy * rinv), d2 = rintf(dz * rinv);
    if (fabsf(d0) <= 1.f && fabsf(d1) <= 1.f && fabsf(d2) <= 1.f) {
      int cube = (int)(d0 + 1.f) * 9 + (int)(d1 + 1.f) * 3 + (int)(d2 + 1.f);
      atomicAdd(&cadd[lvl * 27 + cube], v);
      atomicAdd(&ccnt[lvl * 27 + cube], 1.f);
    }
  }
  unsigned long long pk = (((unsigned long long)f2key(v)) << 32) | (unsigned)t;
  atomicMax(&gmax, pk);
  {
    float d0 = rintf(dx * 0.25f), d1 = rintf(dy * 0.25f), d2 = rintf(dz * 0.25f);
    if (fabsf(d0) <= 1.5f && fabsf(d1) <= 1.5f && fabsf(d2) <= 1.5f) {
      int bin = (int)(d0 + 1.f) * 9 + (int)(d1 + 1.f) * 3 + (int)(d2 + 1.f);
      atomicMax(&cmax[bin], pk);
    }
  }
  __syncthreads();
  if (t < 27) {
    unsigned long long pkb = cmax[t];
    unsigned hi = (unsigned)(pkb >> 32);
    int ob = (hi <= 0x80000000u) ? 1 : 0;
    int ki = ob ? (int)(gmax & 0xFFFFFFFFULL) : (int)(pkb & 0xFFFFFFFFULL);
    float ccx = px[ki], ccy = py[ki], ccz = pz[ki];
    float bx = (float)(t / 9 - 1), by = (float)((t / 3) % 3 - 1), bz = (float)(t % 3 - 1);
    float vk0 = c0 + bx * 4.f, vk1 = c1 + by * 4.f, vk2 = c2 + bz * 4.f;
    float m0 = fminf(fmaxf(ccx - vk0, -1.f), 1.f) + vk0;
    float m1 = fminf(fmaxf(ccy - vk1, -1.f), 1.f) + vk1;
    float m2 = fminf(fmaxf(ccz - vk2, -1.f), 1.f) + vk2;
    mvp[t] = make_float4(m0, m1, m2, ob ? 1.f : 0.f);
    float* vp = vox_in + ((size_t)n * 27 + t) * 4;
    vp[1] = m0; vp[2] = m1; vp[3] = m2;
  }
  __syncthreads();
  int is = 27;
#pragma unroll 1
  for (int b = 0; b < 27; ++b) {
    float4 mv = mvp[b];
    if (mv.w == 0.f && fabsf(p0 - mv.x) <= 1.f && fabsf(p1 - mv.y) <= 1.f &&
        fabsf(p2 - mv.z) <= 1.f)
      is = b;
  }
  atomicAdd(&vadd[is], v);
  atomicAdd(&vcnt[is], 1);
  __syncthreads();
  if (t < 27) {
    float cnt = fmaxf((float)vcnt[t], 1.f);
    vox_in[((size_t)n * 27 + t) * 4 + 0] = vadd[t] / cnt;
  }
  if (t < 81) {
    float cnt = fminf(fmaxf(ccnt[t], 1.f), 8192.f);
    feats[(size_t)t * NPT + n] = cadd[t] / cnt;
  }
  int rank = 0;
#pragma unroll 4
  for (int j4 = 0; j4 < 32; ++j4) {
    float4 dj = dd4s[j4];
    int jb = j4 * 4;
    rank += (dj.x < d || (dj.x == d && jb + 0 < t)) ? 1 : 0;
    rank += (dj.y < d || (dj.y == d && jb + 1 < t)) ? 1 : 0;
    rank += (dj.z < d || (dj.z == d && jb + 2 < t)) ? 1 : 0;
    rank += (dj.w < d || (dj.w == d && jb + 3 < t)) ? 1 : 0;
  }
  if (rank < 32) {
    float* kp = knn_in + ((size_t)n * 32 + rank) * 4;
    *(float4*)kp = make_float4(v, dx, dy, dz);
  }
}

// ---------------- input moments for GN stats (conv is linear) ----------------
__global__ __launch_bounds__(256) void k_moments(const float* __restrict__ vox_in,
                                                 const float* __restrict__ knn_in,
                                                 double* __restrict__ mom) {
  int b = blockIdx.x, t = threadIdx.x;
  int isknn = (b >= 256) ? 1 : 0;
  const float* src = isknn ? knn_in : vox_in;
  int nsite = isknn ? NPT * 32 : NPT * 27;
  int base = isknn ? 14 : 0;
  int bb = isknn ? b - 256 : b;
  float S0 = 0, S1 = 0, S2 = 0, S3 = 0;
  float M00 = 0, M01 = 0, M02 = 0, M03 = 0, M11 = 0, M12 = 0, M13 = 0, M22 = 0, M23 = 0, M33 = 0;
  for (int s = bb * 256 + t; s < nsite; s += 256 * 256) {
    float4 x = *(const float4*)(src + (size_t)s * 4);
    S0 += x.x; S1 += x.y; S2 += x.z; S3 += x.w;
    M00 += x.x * x.x; M01 += x.x * x.y; M02 += x.x * x.z; M03 += x.x * x.w;
    M11 += x.y * x.y; M12 += x.y * x.z; M13 += x.y * x.w;
    M22 += x.z * x.z; M23 += x.z * x.w; M33 += x.w * x.w;
  }
  float vals[14] = {S0, S1, S2, S3, M00, M01, M02, M03, M11, M12, M13, M22, M23, M33};
  for (int off = 32; off; off >>= 1)
#pragma unroll
    for (int i = 0; i < 14; ++i) vals[i] += __shfl_down(vals[i], off);
  __shared__ float part[14];
  if (t < 14) part[t] = 0.f;
  __syncthreads();
  if ((t & 63) == 0)
#pragma unroll
    for (int i = 0; i < 14; ++i) atomicAdd(&part[i], vals[i]);
  __syncthreads();
  if (t < 14) atomicAdd(&mom[base + t], (double)part[t]);
}

// ---------------- finalize GN stats from moments ----------------
__global__ void k_stats_fin(const float* __restrict__ vw1, const float* __restrict__ vb1,
                            const float* __restrict__ kw1, const float* __restrict__ kb1,
                            const double* __restrict__ mom, double* __restrict__ stats) {
  int t = threadIdx.x;
  if (t >= 16) return;
  int isknn = (t >= 8) ? 1 : 0;
  const double* m = mom + (isknn ? 14 : 0);
  const float* W = isknn ? kw1 : vw1;
  const float* Bi = isknn ? kb1 : vb1;
  double N = isknn ? (double)NPT * 32.0 : (double)NPT * 27.0;
  int per = isknn ? 8 : 4;
  int g = isknn ? t - 8 : t;
  double S0 = m[0], S1 = m[1], S2 = m[2], S3 = m[3];
  double M00 = m[4], M01 = m[5], M02 = m[6], M03 = m[7];
  double M11 = m[8], M12 = m[9], M13 = m[10], M22 = m[11], M23 = m[12], M33 = m[13];
  double sum = 0.0, ssq = 0.0;
  for (int k = 0; k < per; ++k) {
    int oc = g * per + k;
    double w0 = W[oc * 4 + 0], w1 = W[oc * 4 + 1], w2 = W[oc * 4 + 2], w3 = W[oc * 4 + 3];
    double b = Bi[oc];
    double ws = w0 * S0 + w1 * S1 + w2 * S2 + w3 * S3;
    double q = w0 * w0 * M00 + w1 * w1 * M11 + w2 * w2 * M22 + w3 * w3 * M33 +
               2.0 * (w0 * w1 * M01 + w0 * w2 * M02 + w0 * w3 * M03 +
                      w1 * w2 * M12 + w1 * w3 * M13 + w2 * w3 * M23);
    sum += ws + N * b;
    ssq += q + 2.0 * b * ws + N * b * b;
  }
  double* out = stats + (isknn ? 16 : 0);
  out[2 * g + 0] = sum;
  out[2 * g + 1] = ssq;
}

// ---------------- vox branch apply ----------------
__global__ __launch_bounds__(256) void k_vox_apply(const float* __restrict__ vox_in,
                                                   const float* __restrict__ w1,
                                                   const float* __restrict__ b1,
                                                   const float* __restrict__ gamma,
                                                   const float* __restrict__ beta,
                                                   const float* __restrict__ pr,
                                                   const float* __restrict__ w2,
                                                   const float* __restrict__ b2,
                                                   const double* __restrict__ stats,
                                                   float* __restrict__ feats) {
  int s = blockIdx.x * 256 + threadIdx.x;
  if (s >= NPT * 27) return;
  float mean[8], rstd[8];
  const double cntd = 4.0 * 8192.0 * 27.0;
#pragma unroll
  for (int g = 0; g < 8; ++g) {
    double m = stats[2 * g] / cntd;
    double var = stats[2 * g + 1] / cntd - m * m;
    mean[g] = (float)m;
    rstd[g] = (float)(1.0 / sqrt(var + 1e-5));
  }
  float a = pr[0];
  float4 in = *(const float4*)(vox_in + (size_t)s * 4);
  float out = b2[0];
#pragma unroll
  for (int oc = 0; oc < 32; ++oc) {
    float4 w = *(const float4*)(w1 + oc * 4);
    float h = w.x * in.x + w.y * in.y + w.z * in.z + w.w * in.w + b1[oc];
    int g = oc >> 2;
    float xn = (h - mean[g]) * rstd[g] * gamma[oc] + beta[oc];
    float y = (xn >= 0.f) ? xn : a * xn;
    out += w2[oc] * y;
  }
  int n = s / 27, bb = s - n * 27;
  feats[(size_t)(81 + bb) * NPT + n] = out;
}

// ---------------- knn apply: GN+PReLU, max over 32 -> kf (64 x N) ----------------
__global__ __launch_bounds__(256) void k_knn_max(const float* __restrict__ knn_in,
                                                 const float* __restrict__ w1,
                                                 const float* __restrict__ b1,
                                                 const float* __restrict__ gamma,
                                                 const float* __restrict__ beta,
                                                 const float* __restrict__ pr,
                                                 const double* __restrict__ stats,
                                                 float* __restrict__ kf) {
  int tid0 = blockIdx.x * 256 + threadIdx.x;
  int n = tid0 & (NPT - 1);
  int oc = tid0 >> 13;
  const double cntd = 8.0 * 8192.0 * 32.0;
  int g = oc >> 3;
  double md = stats[2 * g] / cntd;
  double var = stats[2 * g + 1] / cntd - md * md;
  float mean = (float)md, rstd = (float)(1.0 / sqrt(var + 1e-5));
  float4 w = *(const float4*)(w1 + oc * 4);
  float bb = b1[oc], ga = gamma[oc], be = beta[oc], a = pr[0];
  float mx = -INFINITY;
  for (int j = 0; j < 32; ++j) {
    float4 in = *(const float4*)(knn_in + ((size_t)n * 32 + j) * 4);
    float h = w.x * in.x + w.y * in.y + w.z * in.z + w.w * in.w + bb;
    float xn = (h - mean) * rstd * ga + be;
    float y = (xn >= 0.f) ? xn : a * xn;
    mx = fmaxf(mx, y);
  }
  kf[(size_t)oc * NPT + n] = mx;
}

// ---------------- out branch conv1 (108->128) + GN stats ----------------
__global__ __launch_bounds__(256) void k_out1(const float* __restrict__ feats,
                                              const float* __restrict__ w1,
                                              const float* __restrict__ b1,
                                              float* __restrict__ h1,
                                              double* __restrict__ stats) {
  __shared__ float wlds[108 * 16];
  __shared__ float ls, lq;
  int t = threadIdx.x;
  int ocb = blockIdx.y * 16;
  for (int i = t; i < 108 * 16; i += 256) {
    int j = i / 108, ic = i - j * 108;
    wlds[ic * 16 + j] = w1[ocb * 108 + i];
  }
  if (t == 0) { ls = 0.f; lq = 0.f; }
  __syncthreads();
  int n = blockIdx.x * 256 + t;
  float acc[16];
#pragma unroll
  for (int j = 0; j < 16; ++j) acc[j] = b1[ocb + j];
#pragma unroll 4
  for (int ic = 0; ic < 108; ++ic) {
    float v = feats[(size_t)ic * NPT + n];
    const float4* w4 = (const float4*)(wlds + ic * 16);
#pragma unroll
    for (int q = 0; q < 4; ++q) {
      float4 w = w4[q];
      acc[q * 4 + 0] += w.x * v; acc[q * 4 + 1] += w.y * v;
      acc[q * 4 + 2] += w.z * v; acc[q * 4 + 3] += w.w * v;
    }
  }
  float s = 0.f, q = 0.f;
#pragma unroll
  for (int j = 0; j < 16; ++j) {
    h1[(size_t)(ocb + j) * NPT + n] = acc[j];
    s += acc[j]; q += acc[j] * acc[j];
  }
  for (int off = 32; off; off >>= 1) { s += __shfl_down(s, off); q += __shfl_down(q, off); }
  if ((t & 63) == 0) { atomicAdd(&ls, s); atomicAdd(&lq, q); }
  __syncthreads();
  if (t == 0) {
    atomicAdd(&stats[2 * blockIdx.y + 0], (double)ls);
    atomicAdd(&stats[2 * blockIdx.y + 1], (double)lq);
  }
}

// ---------------- final: GN+PReLU on h1, conv(128->64) + conv(64->64)(kf) ----------------
__global__ __launch_bounds__(256) void k_final(const float* __restrict__ h1,
                                               const float* __restrict__ kf,
                                               const float* __restrict__ gamma,
                                               const float* __restrict__ beta,
                                               const float* __restrict__ pr,
                                               const float* __restrict__ w2,
                                               const float* __restrict__ b2,
                                               const float* __restrict__ kow,
                                               const float* __restrict__ kob,
                                               const double* __restrict__ stats,
                                               float* __restrict__ out) {
  __shared__ float wl[192 * 8];
  __shared__ float scl[128], sft[128];
  int t = threadIdx.x;
  int ocb = blockIdx.y * 8;
  for (int i = t; i < 128 * 8; i += 256) {
    int j = i >> 7, ic = i & 127;
    wl[ic * 8 + j] = w2[(ocb + j) * 128 + ic];
  }
  for (int i = t; i < 64 * 8; i += 256) {
    int j = i >> 6, ic = i & 63;
    wl[(128 + ic) * 8 + j] = kow[(ocb + j) * 64 + ic];
  }
  if (t < 128) {
    const double cntd = 16.0 * 8192.0;
    int g = t >> 4;
    double m = stats[2 * g] / cntd;
    double var = stats[2 * g + 1] / cntd - m * m;
    float rs = (float)(1.0 / sqrt(var + 1e-5));
    float ga = gamma[t];
    scl[t] = rs * ga;
    sft[t] = beta[t] - (float)m * rs * ga;
  }
  __syncthreads();
  int n = blockIdx.x * 256 + t;
  float a = pr[0];
  float acc[8];
#pragma unroll
  for (int j = 0; j < 8; ++j) acc[j] = b2[ocb + j] + kob[ocb + j];
#pragma unroll 2
  for (int ic = 0; ic < 128; ++ic) {
    float x = h1[(size_t)ic * NPT + n];
    float xn = x * scl[ic] + sft[ic];
    float y = (xn >= 0.f) ? xn : a * xn;
    const float4* w4 = (const float4*)(wl + ic * 8);
    float4 wa = w4[0], wb = w4[1];
    acc[0] += wa.x * y; acc[1] += wa.y * y; acc[2] += wa.z * y; acc[3] += wa.w * y;
    acc[4] += wb.x * y; acc[5] += wb.y * y; acc[6] += wb.z * y; acc[7] += wb.w * y;
  }
#pragma unroll 2
  for (int ic = 0; ic < 64; ++ic) {
    float y = kf[(size_t)ic * NPT + n];
    const float4* w4 = (const float4*)(wl + (128 + ic) * 8);
    float4 wa = w4[0], wb = w4[1];
    acc[0] += wa.x * y; acc[1] += wa.y * y; acc[2] += wa.z * y; acc[3] += wa.w * y;
    acc[4] += wb.x * y; acc[5] += wb.y * y; acc[6] += wb.z * y; acc[7] += wb.w * y;
  }
#pragma unroll
  for (int j = 0; j < 8; ++j)
    out[(size_t)(ocb + j) * NPT + n] = acc[j];
}

extern "C" void kernel_launch(void* const* d_in, const int* in_sizes, int n_in,
                              void* d_out, int out_size, void* d_ws, size_t ws_size,
                              hipStream_t stream) {
  (void)in_sizes; (void)n_in; (void)out_size;
  const float* fmap1  = (const float*)d_in[0];
  const float* fmap2  = (const float*)d_in[1];
  const float* xyz2   = (const float*)d_in[2];
  const float* coords = (const float*)d_in[3];
  const float* out_w1 = (const float*)d_in[4];
  const float* out_b1 = (const float*)d_in[5];
  const float* out_g  = (const float*)d_in[6];
  const float* out_bt = (const float*)d_in[7];
  const float* out_pr = (const float*)d_in[8];
  const float* out_w2 = (const float*)d_in[9];
  const float* out_b2 = (const float*)d_in[10];
  const float* vox_w1 = (const float*)d_in[11];
  const float* vox_b1 = (const float*)d_in[12];
  const float* vox_g  = (const float*)d_in[13];
  const float* vox_bt = (const float*)d_in[14];
  const float* vox_pr = (const float*)d_in[15];
  const float* vox_w2 = (const float*)d_in[16];
  const float* vox_b2 = (const float*)d_in[17];
  const float* knn_w1 = (const float*)d_in[18];
  const float* knn_b1 = (const float*)d_in[19];
  const float* knn_g  = (const float*)d_in[20];
  const float* knn_bt = (const float*)d_in[21];
  const float* knn_pr = (const float*)d_in[22];
  const float* knn_ow = (const float*)d_in[23];
  const float* knn_ob = (const float*)d_in[24];

  float* ws = (float*)d_ws;
  // nonslab floats: tcorr+tidx+feats+vox_in+knn_in+h1+kf (6,488,064)
  //               + 6 bf16-split arrays (3,145,728 float-equiv)
  const size_t nonslab = 6488064ull + 3145728ull;
  int SR;
  if (ws_size >= (8388608ull + nonslab) * 4ull + 2048ull) SR = 1024;
  else if (ws_size >= (4194304ull + nonslab) * 4ull + 2048ull) SR = 512;
  else SR = 256;

  float* slab   = ws;
  float* tcorr  = slab + (size_t)SR * NPT;
  int*   tidx   = (int*)(tcorr + (size_t)NPT * KK);
  float* feats  = tcorr + (size_t)NPT * KK * 2;
  float* vox_in = feats + 108 * NPT;
  float* knn_in = vox_in + (size_t)NPT * 27 * 4;
  float* h1     = knn_in + (size_t)NPT * 32 * 4;
  float* kf     = h1 + 128 * NPT;
  double* stats = (double*)(kf + 64 * NPT);
  double* mom   = stats + 48;
  short* a0s    = (short*)(mom + 28);            // each split: 8192*128 shorts
  short* a1s    = a0s + (size_t)NPT * CCH;
  short* a2s    = a1s + (size_t)NPT * CCH;
  short* b0s    = a2s + (size_t)NPT * CCH;
  short* b1s    = b0s + (size_t)NPT * CCH;
  short* b2s    = b1s + (size_t)NPT * CCH;

  hipLaunchKernelGGL(k_zero, dim3(1), dim3(128), 0, stream, stats);
  hipLaunchKernelGGL(k_split, dim3(NPT / 16), dim3(256), 0, stream, fmap1, a0s, a1s, a2s);
  hipLaunchKernelGGL(k_split, dim3(NPT / 16), dim3(256), 0, stream, fmap2, b0s, b1s, b2s);
  int iters = NPT / SR;
  for (int s = 0; s < iters; ++s) {
    hipLaunchKernelGGL(k_gemm_mfma, dim3(NPT / 128, SR / 64), dim3(256), 0, stream,
                       a0s, a1s, a2s, b0s, b1s, b2s, slab, s * SR);
    hipLaunchKernelGGL(k_select, dim3(SR), dim3(256), 0, stream, slab, s * SR, tcorr, tidx);
  }
  hipLaunchKernelGGL(k_point, dim3(NPT), dim3(128), 0, stream, tcorr, tidx, xyz2, coords,
                     feats, vox_in, knn_in);
  hipLaunchKernelGGL(k_moments, dim3(512), dim3(256), 0, stream, vox_in, knn_in, mom);
  hipLaunchKernelGGL(k_stats_fin, dim3(1), dim3(64), 0, stream, vox_w1, vox_b1, knn_w1, knn_b1,
                     mom, stats);
  hipLaunchKernelGGL(k_vox_apply, dim3((NPT * 27 + 255) / 256), dim3(256), 0, stream, vox_in,
                     vox_w1, vox_b1, vox_g, vox_bt, vox_pr, vox_w2, vox_b2, stats, feats);
  hipLaunchKernelGGL(k_knn_max, dim3(64 * NPT / 256), dim3(256), 0, stream, knn_in, knn_w1,
                     knn_b1, knn_g, knn_bt, knn_pr, stats + 16, kf);
  hipLaunchKernelGGL(k_out1, dim3(32, 8), dim3(256), 0, stream, feats, out_w1, out_b1, h1,
                     stats + 32);
  hipLaunchKernelGGL(k_final, dim3(32, 8), dim3(256), 0, stream, h1, kf, out_g, out_bt,
                     out_pr, out_w2, out_b2, knn_ow, knn_ob, stats + 32, (float*)d_out);
}